// Round 14
// baseline (290.412 us; speedup 1.0000x reference)
//
#include <hip/hip_runtime.h>

#define NV 10000
#define NB 4
#define NTT 12
#define NSEQ 48
#define NH 3
#define NE 512
#define NS 32
#define ND 64
#define NVT 313   // ceil(NV/32) 32-seq tiles

// ---- fixed workspace layout (element indices; float and int regions share the base) ----
#define S_U   0
#define S_C1  64
#define S_V1  128
#define S_V2  192
#define S_SC  256
#define S_GU  272
#define S_GC  528
#define S_G0  784
#define F_INV 1040
#define F_M   (F_INV + NH*NV)            // 31040
#define F_PQ  (F_M + NH*NV)              // 61040  (holds 2*NV*NSEQ u32 packed pq)
#define F_HT  (F_PQ + 4*NV*NSEQ)         // (spare)
#define I_CNT (F_HT + 2*NB*NV)           // 2061040
#define I_CUR (I_CNT + NH*NV)
#define I_OFF (I_CUR + NH*NV)
#define I_SLOT (I_OFF + NH*NV)
#define F_DYN (I_SLOT + NH*NE*NS)        // 2200192
#define XT_SZ  (NV*NSEQ)                 // 480000
#define AGG_SZ (NH*NE*NSEQ)              // 73728
#define YZ_SZ  (NH*NV*NSEQ)              // 1440000
#define B_SZ   (NH*NE*NE)                // 786432 (B lives in dead YZ region, batched path)

#define NZERO (2*NH*NV + NB*NV)          // ints zeroed (cnt+cur) + floats zeroed (out)
#define ZBLK  ((NZERO + 255) / 256)      // 391 zero blocks (non-batched)
#define TRB   ((NV + 127) / 128)         // 79 transpose tiles per branch

#define L2E 1.442695040888963f           // log2(e)

typedef __attribute__((ext_vector_type(8))) _Float16 f16x8;
typedef __attribute__((ext_vector_type(4))) float f32x4;

__device__ __forceinline__ unsigned short f2h(float x) {
  union { _Float16 h; unsigned short u; } c;
  c.h = (_Float16)x;   // v_cvt_f16_f32, RNE
  return c.u;
}
__device__ __forceinline__ f16x8 ldsH(const unsigned short* p) {
  union { uint4 u; f16x8 v; } x;
  x.u = *(const uint4*)p;
  return x.v;
}

// ---------------- merged: weight precompute (block 0) + zeroing + input transpose ----------------
// zblk = number of zeroing blocks; nz = total elements to zero (cnt,cur,out[,B]).
__global__ void k_init(const float* __restrict__ w1, const float* __restrict__ b1,
                       const float* __restrict__ w2, const float* __restrict__ b2,
                       const float* __restrict__ attn_w, const float* __restrict__ attn_a,
                       const float* __restrict__ w_ih, const float* __restrict__ b_ih,
                       const float* __restrict__ b_hh, float* __restrict__ ws,
                       int* __restrict__ cnt, float* __restrict__ out,
                       const float* __restrict__ s0, const float* __restrict__ s1,
                       float* __restrict__ xT, int xtS,
                       float* __restrict__ bz, int nz, int zblk) {
  const int tid = threadIdx.x;
  if (blockIdx.x > zblk) {
    // transpose seq [48][NV] -> xT [NV][48], 128-vertex tiles
    __shared__ float tile[128][49];
    const int bx = blockIdx.x - 1 - zblk;
    const int brn = bx / TRB;
    const int v0 = (bx % TRB) * 128;
    const float* seq = brn ? s1 : s0;
    float* o = xT + (size_t)brn * xtS;
    for (int i = tid; i < 128 * NSEQ; i += 256) {
      const int n = i / 128, vl = i % 128;
      const int v = v0 + vl;
      tile[vl][n] = (v < NV) ? seq[n * NV + v] : 0.0f;
    }
    __syncthreads();
    for (int i = tid; i < 128 * NSEQ; i += 256) {
      const int vl = i / NSEQ, n = i % NSEQ;
      const int v = v0 + vl;
      if (v < NV) o[v * NSEQ + n] = tile[vl][n];
    }
    return;
  }
  if (blockIdx.x != 0) {
    const int g = (blockIdx.x - 1) * 256 + tid;
    if (g < 2 * NH * NV) cnt[g] = 0;
    else if (g < NZERO) out[g - 2 * NH * NV] = 0.0f;
    else if (g < nz) bz[g - NZERO] = 0.0f;
    return;
  }
  __shared__ float u_s[64], c1_s[64];
  if (tid < 64) {
    float v1 = 0.f, v2 = 0.f, u = 0.f, c1 = 0.f;
    for (int d = 0; d < 64; ++d) {
      const float aw = attn_w[tid * 64 + d];
      v1 += aw * attn_a[d];
      v2 += aw * attn_a[64 + d];
      const float w2v = w2[d * 64 + tid];
      u  += w1[d] * w2v;
      c1 += b1[d] * w2v;
    }
    ws[S_U + tid] = u;  ws[S_C1 + tid] = c1;
    ws[S_V1 + tid] = v1; ws[S_V2 + tid] = v2;
    u_s[tid] = u; c1_s[tid] = c1;
  }
  __syncthreads();
  if (tid == 0) {
    float al = 0.f, be = 0.f, ga = 0.f, de = 0.f, ep = 0.f;
    for (int d = 0; d < 64; ++d) {
      const float v1 = ws[S_V1 + d], v2 = ws[S_V2 + d];
      al += u_s[d] * v1;  be += c1_s[d] * v1;
      ga += u_s[d] * v2;  de += c1_s[d] * v2;
      ep += b2[d] * (v1 + v2);
    }
    ws[S_SC + 0] = al; ws[S_SC + 1] = be; ws[S_SC + 2] = ga;
    ws[S_SC + 3] = de; ws[S_SC + 4] = ep;
  }
  {
    const int j = tid;  // 256 threads exactly
    float gu = 0.f, gc = 0.f, g0 = 0.f;
    for (int d = 0; d < 64; ++d) {
      const float w = w_ih[j * 64 + d];
      gu += w * u_s[d]; gc += w * c1_s[d]; g0 += w * b2[d];
    }
    ws[S_GU + j] = gu; ws[S_GC + j] = gc;
    ws[S_G0 + j] = g0 + b_ih[j] + b_hh[j];
  }
}

// ---------------- graph structure ----------------
__global__ void k_count(const int* __restrict__ edges, int* __restrict__ counts) {
  const int g = blockIdx.x * 256 + threadIdx.x;
  if (g >= NH * NE * NS) return;
  const int h = g >> 14;
  atomicAdd(&counts[h * NV + edges[g]], 1);
}

__global__ void k_scan(const int* __restrict__ counts, int* __restrict__ offs,
                       float* __restrict__ invdeg, float* __restrict__ mvec) {
  const int h = blockIdx.x;
  const int tid = threadIdx.x;  // 1024 threads
  const int base = h * NV;
  const int CH = 10;
  int local[10];
  int run = 0;
  for (int i = 0; i < CH; ++i) {
    const int v = tid * CH + i;
    const int c = (v < NV) ? counts[base + v] : 0;
    local[i] = run; run += c;
  }
  __shared__ int sd[1024];
  sd[tid] = run;
  __syncthreads();
  int acc = run;
  for (int off = 1; off < 1024; off <<= 1) {
    const int t = (tid >= off) ? sd[tid - off] : 0;
    __syncthreads();
    acc += t; sd[tid] = acc;
    __syncthreads();
  }
  const int excl = acc - run;
  for (int i = 0; i < CH; ++i) {
    const int v = tid * CH + i;
    if (v < NV) {
      offs[base + v] = excl + local[i];
      const int c = counts[base + v];
      invdeg[base + v] = 1.0f / (float)((c > 0) ? c : 1);
      mvec[base + v] = (c > 0) ? 1.0f : 0.0f;
    }
  }
}

// ---- fused: CSR fill (blocks [0,192)) || eagg1 both branches (blocks [192,1344)) ----
__global__ void k_fe1(const int* __restrict__ edges, const int* __restrict__ offs,
                      int* __restrict__ cursor, int* __restrict__ slot_edge,
                      const float* __restrict__ xT, int xtS,
                      float* __restrict__ agg, int aggS) {
  const int tid = threadIdx.x;
  if (blockIdx.x < 192) {
    const int g = blockIdx.x * 256 + tid;   // == NH*NE*NS exactly at 192*256
    const int h = g >> 14;
    const int e = (g >> 5) & (NE - 1);
    const int v = edges[g];
    const int pos = atomicAdd(&cursor[h * NV + v], 1);
    slot_edge[h * NE * NS + offs[h * NV + v] + pos] = e;
    return;
  }
  const int job = blockIdx.x - 192;         // 0..1151
  const int brn = job / 576;
  const int g = (job % 576) * 256 + tid;    // < NH*NE*12*8 exactly
  const float* x = xT + (size_t)brn * xtS;
  float* a = agg + (size_t)brn * aggS;
  const int sub = g & 7;
  const int o = g >> 3;
  const int n0 = (o % 12) * 4;
  const int e = (o / 12) % NE;
  const int h = o / (12 * NE);
  const int* ep = edges + (h * NE + e) * NS + sub * 4;
  float4 acc = make_float4(0.f, 0.f, 0.f, 0.f);
  #pragma unroll
  for (int s = 0; s < 4; ++s) {
    const float4 t = *(const float4*)&x[ep[s] * NSEQ + n0];
    acc.x += t.x; acc.y += t.y; acc.z += t.z; acc.w += t.w;
  }
  #pragma unroll
  for (int m = 1; m < 8; m <<= 1) {
    acc.x += __shfl_xor(acc.x, m);
    acc.y += __shfl_xor(acc.y, m);
    acc.z += __shfl_xor(acc.z, m);
    acc.w += __shfl_xor(acc.w, m);
  }
  if (sub == 0) {
    acc.x *= (1.0f / NS); acc.y *= (1.0f / NS); acc.z *= (1.0f / NS); acc.w *= (1.0f / NS);
    *(float4*)&a[(h * NE + e) * NSEQ + n0] = acc;
  }
}

// ---- B-operator build: B[h][e][e'] = sum_v A[e][v]*invdeg[v]*A[e'][v] via CSR pairs ----
__global__ void k_bmat(const int* __restrict__ counts, const int* __restrict__ offs,
                       const int* __restrict__ slot_edge, const float* __restrict__ invdeg,
                       float* __restrict__ Bm) {
  const int g = blockIdx.x * 256 + threadIdx.x;
  if (g >= NH * NV) return;
  const int c = counts[g];
  if (c == 0) return;
  const int h = g / NV;
  const int beg = offs[g];
  const int* se = slot_edge + h * NE * NS;
  const float iv = invdeg[g];
  for (int i = 0; i < c; ++i) {
    float* row = Bm + ((size_t)(h * NE + se[beg + i])) * NE;
    for (int j = 0; j < c; ++j)
      atomicAdd(&row[se[beg + j]], iv);
  }
}

// ---- agg2 = (1/32) * B @ agg1  (dense 512x512x48 per head per branch) ----
// replaces k_vg(stage1) + k_eagg2: same algebra, regular strided loads instead of
// CSR scattered gathers. 8 lanes per output (K split 8x64), shuffle-reduced.
__global__ void k_gemm(const float* __restrict__ Bm, const float* __restrict__ agg1,
                       int aggS, float* __restrict__ agg2, int agg2S) {
  const int g = blockIdx.x * 256 + threadIdx.x;
  if (g >= NH * NE * 12 * 8) return;
  const int brn = blockIdx.y;
  const int sub = g & 7;
  const int o = g >> 3;
  const int n0 = (o % 12) * 4;
  const int e = (o / 12) % NE;
  const int h = o / (12 * NE);
  const float* a1 = agg1 + (size_t)brn * aggS + h * NE * NSEQ;   // [512][48]
  const float* brow = Bm + ((size_t)(h * NE + e)) * NE + sub * 64;
  float4 acc = make_float4(0.f, 0.f, 0.f, 0.f);
  #pragma unroll 4
  for (int k = 0; k < 64; ++k) {
    const float b = brow[k];
    const float4 t = *(const float4*)&a1[(sub * 64 + k) * NSEQ + n0];
    acc.x = fmaf(b, t.x, acc.x); acc.y = fmaf(b, t.y, acc.y);
    acc.z = fmaf(b, t.z, acc.z); acc.w = fmaf(b, t.w, acc.w);
  }
  #pragma unroll
  for (int m = 1; m < 8; m <<= 1) {
    acc.x += __shfl_xor(acc.x, m);
    acc.y += __shfl_xor(acc.y, m);
    acc.z += __shfl_xor(acc.z, m);
    acc.w += __shfl_xor(acc.w, m);
  }
  if (sub == 0) {
    acc.x *= (1.0f / NS); acc.y *= (1.0f / NS); acc.z *= (1.0f / NS); acc.w *= (1.0f / NS);
    *(float4*)&agg2[(size_t)brn * agg2S + (h * NE + e) * NSEQ + n0] = acc;
  }
}

// separate fill / eagg1 / vg / eagg2 (non-batched fallback path only)
__global__ void k_fill(const int* __restrict__ edges, const int* __restrict__ offs,
                       int* __restrict__ cursor, int* __restrict__ slot_edge) {
  const int g = blockIdx.x * 256 + threadIdx.x;
  if (g >= NH * NE * NS) return;
  const int h = g >> 14;
  const int e = (g >> 5) & (NE - 1);
  const int v = edges[g];
  const int pos = atomicAdd(&cursor[h * NV + v], 1);
  slot_edge[h * NE * NS + offs[h * NV + v] + pos] = e;
}

__global__ void k_eagg1(const int* __restrict__ edges, const float* __restrict__ xT,
                        int xtS, float* __restrict__ agg, int aggS) {
  const int g = blockIdx.x * 256 + threadIdx.x;
  if (g >= NH * NE * 12 * 8) return;
  const float* x = xT + (size_t)blockIdx.y * xtS;
  float* a = agg + (size_t)blockIdx.y * aggS;
  const int sub = g & 7;
  const int o = g >> 3;
  const int n0 = (o % 12) * 4;
  const int e = (o / 12) % NE;
  const int h = o / (12 * NE);
  const int* ep = edges + (h * NE + e) * NS + sub * 4;
  float4 acc = make_float4(0.f, 0.f, 0.f, 0.f);
  #pragma unroll
  for (int s = 0; s < 4; ++s) {
    const float4 t = *(const float4*)&x[ep[s] * NSEQ + n0];
    acc.x += t.x; acc.y += t.y; acc.z += t.z; acc.w += t.w;
  }
  #pragma unroll
  for (int m = 1; m < 8; m <<= 1) {
    acc.x += __shfl_xor(acc.x, m);
    acc.y += __shfl_xor(acc.y, m);
    acc.z += __shfl_xor(acc.z, m);
    acc.w += __shfl_xor(acc.w, m);
  }
  if (sub == 0) {
    acc.x *= (1.0f / NS); acc.y *= (1.0f / NS); acc.z *= (1.0f / NS); acc.w *= (1.0f / NS);
    *(float4*)&a[(h * NE + e) * NSEQ + n0] = acc;
  }
}

__global__ void k_eagg2(const int* __restrict__ edges, const float* __restrict__ ysum,
                        int yS, const float* __restrict__ invdeg,
                        float* __restrict__ agg, int aggS) {
  const int g = blockIdx.x * 256 + threadIdx.x;
  if (g >= NH * NE * 12 * 8) return;
  const float* y = ysum + (size_t)blockIdx.y * yS;
  float* a = agg + (size_t)blockIdx.y * aggS;
  const int sub = g & 7;
  const int o = g >> 3;
  const int n0 = (o % 12) * 4;
  const int e = (o / 12) % NE;
  const int h = o / (12 * NE);
  const int* ep = edges + (h * NE + e) * NS + sub * 4;
  float4 acc = make_float4(0.f, 0.f, 0.f, 0.f);
  #pragma unroll
  for (int s = 0; s < 4; ++s) {
    const int v = ep[s];
    const float iv = invdeg[h * NV + v];
    const float4 t = *(const float4*)&y[(h * NV + v) * NSEQ + n0];
    acc.x += t.x * iv; acc.y += t.y * iv; acc.z += t.z * iv; acc.w += t.w * iv;
  }
  #pragma unroll
  for (int m = 1; m < 8; m <<= 1) {
    acc.x += __shfl_xor(acc.x, m);
    acc.y += __shfl_xor(acc.y, m);
    acc.z += __shfl_xor(acc.z, m);
    acc.w += __shfl_xor(acc.w, m);
  }
  if (sub == 0) {
    acc.x *= (1.0f / NS); acc.y *= (1.0f / NS); acc.z *= (1.0f / NS); acc.w *= (1.0f / NS);
    *(float4*)&a[(h * NE + e) * NSEQ + n0] = acc;
  }
}

__global__ void k_vg(const int* __restrict__ counts, const int* __restrict__ offs,
                     const int* __restrict__ slot_edge, const float* __restrict__ agg,
                     int aggS, float* __restrict__ outv, int outS) {
  const int g = blockIdx.x * 256 + threadIdx.x;
  if (g >= NH * NV * 12) return;
  const float* a = agg + (size_t)blockIdx.y * aggS;
  float* o = outv + (size_t)blockIdx.y * outS;
  const int n0 = (g % 12) * 4;
  const int v = (g / 12) % NV;
  const int h = g / (12 * NV);
  const int beg = offs[h * NV + v];
  const int cnt = counts[h * NV + v];
  const int* se = slot_edge + h * NE * NS;
  float4 acc = make_float4(0.f, 0.f, 0.f, 0.f);
  for (int i = 0; i < cnt; ++i) {
    const int e = se[beg + i];
    const float4 t = *(const float4*)&a[(h * NE + e) * NSEQ + n0];
    acc.x += t.x; acc.y += t.y; acc.z += t.z; acc.w += t.w;
  }
  *(float4*)&o[(h * NV + v) * NSEQ + n0] = acc;
}

// ---- fused stage-2 vertex gather + attention; writes packed f16 (p,q) pairs ----
__global__ void k_vgattn(const int* __restrict__ counts, const int* __restrict__ offs,
                         const int* __restrict__ slot_edge, const float* __restrict__ agg,
                         int aggS, const float* __restrict__ invdeg,
                         const float* __restrict__ mvec, const float* __restrict__ ws,
                         unsigned int* __restrict__ pq, int br0) {
  const int g = blockIdx.x * 256 + threadIdx.x;
  if (g >= NV * 12) return;
  const int bi = blockIdx.y;
  const float* a = agg + (size_t)bi * aggS;
  unsigned int* pbuf = pq + (size_t)(bi + br0) * NV * NSEQ;
  const int n0 = (g % 12) * 4;
  const int v = g / 12;
  const float al = ws[S_SC + 0], be = ws[S_SC + 1], ga = ws[S_SC + 2],
              de = ws[S_SC + 3], ep = ws[S_SC + 4];
  union { float4 v4; float f[4]; } zh[3];
  float mh[3];
  #pragma unroll
  for (int h = 0; h < NH; ++h) {
    const int beg = offs[h * NV + v];
    const int cnt = counts[h * NV + v];
    const int* se = slot_edge + h * NE * NS;
    float4 acc = make_float4(0.f, 0.f, 0.f, 0.f);
    for (int i = 0; i < cnt; ++i) {
      const int e = se[beg + i];
      const float4 t = *(const float4*)&a[(h * NE + e) * NSEQ + n0];
      acc.x += t.x; acc.y += t.y; acc.z += t.z; acc.w += t.w;
    }
    const float iv = invdeg[h * NV + v];
    zh[h].v4 = make_float4(acc.x * iv, acc.y * iv, acc.z * iv, acc.w * iv);
    mh[h] = mvec[h * NV + v];
  }
  const float mb = (mh[0] + mh[1] + mh[2]) * (1.f / 3.f);
  uint4 o4;
  unsigned int* op = (unsigned int*)&o4;
  #pragma unroll
  for (int j = 0; j < 4; ++j) {
    const float z0 = zh[0].f[j], z1 = zh[1].f[j], z2 = zh[2].f[j];
    const float zb = (z0 + z1 + z2) * (1.f / 3.f);
    float sc[3];
    const float zt[3] = {z0, z1, z2};
    #pragma unroll
    for (int h = 0; h < NH; ++h) {
      const float s = al * zt[h] + be * mh[h] + ga * zb + de * mb + ep;
      sc[h] = (s > 0.f) ? s : 0.2f * s;
    }
    const float mx = fmaxf(sc[0], fmaxf(sc[1], sc[2]));
    const float e0 = __expf(sc[0] - mx), e1 = __expf(sc[1] - mx), e2 = __expf(sc[2] - mx);
    const float inv = 1.0f / (e0 + e1 + e2);
    const float pv = (e0 * z0 + e1 * z1 + e2 * z2) * inv;
    const float qv = (e0 * mh[0] + e1 * mh[1] + e2 * mh[2]) * inv;
    op[j] = (unsigned int)f2h(pv) | ((unsigned int)f2h(qv) << 16);
  }
  *(uint4*)&pbuf[v * NSEQ + n0] = o4;
}

// ---------------- MFMA LSTM (R11-verified; unchanged) ----------------
#define RS2 72  // h row stride (ushorts): 64 + 8 pad, 144 B (16B-aligned rows)
__launch_bounds__(256, 4)
__global__ void k_lstm2(const float* __restrict__ w_hh, const float* __restrict__ ws,
                        const unsigned int* __restrict__ pqbase,
                        const float* __restrict__ w_out, const float* __restrict__ b_out,
                        float* __restrict__ out) {
  __shared__ __align__(16) unsigned short smem[2 * 32 * RS2];  // 9216 B h double-buffer
  __shared__ unsigned int pq_sh[NTT][32];                      // packed (p,q) f16, 1536 B
  const int tid = threadIdx.x;
  const int w = tid >> 6, lane = tid & 63, q = lane >> 4, l15 = lane & 15;
  const int bid = blockIdx.x;
  const int vt = bid % NVT;
  const int b  = (bid / NVT) % NB;
  const int br = bid / (NVT * NB);
  const int v0 = vt * 32;
  const int d = w * 16 + l15;  // this lane's gate-dim within [0,64)

  union HU { uint4 u; f16x8 v; };

  // stage packed pq for all 12 steps (uint4 over t): 96 uint4
  const unsigned int* pqb = pqbase + (size_t)br * NV * NSEQ;
  if (tid < 96) {
    const int s = tid / 3, f4 = tid % 3;
    const int v = v0 + s;
    uint4 val = make_uint4(0u, 0u, 0u, 0u);
    if (v < NV) val = *(const uint4*)&pqb[v * NSEQ + b * NTT + f4 * 4];
    pq_sh[f4 * 4 + 0][s] = val.x; pq_sh[f4 * 4 + 1][s] = val.y;
    pq_sh[f4 * 4 + 2][s] = val.z; pq_sh[f4 * 4 + 3][s] = val.w;
  }

  // B fragments direct from global; prescale I/F/O by -log2e, G by -2*log2e.
  f16x8 Bf[4][2];
  #pragma unroll
  for (int g = 0; g < 4; ++g) {
    const float sc = (g == 2) ? (-2.0f * L2E) : -L2E;
    #pragma unroll
    for (int kh = 0; kh < 2; ++kh) {
      const float* wp = w_hh + (g * 64 + d) * 64 + kh * 32 + q * 8;
      const float4 lo = *(const float4*)wp;
      const float4 hi = *(const float4*)(wp + 4);
      HU f;
      f.u.x = (unsigned int)f2h(sc * lo.x) | ((unsigned int)f2h(sc * lo.y) << 16);
      f.u.y = (unsigned int)f2h(sc * lo.z) | ((unsigned int)f2h(sc * lo.w) << 16);
      f.u.z = (unsigned int)f2h(sc * hi.x) | ((unsigned int)f2h(sc * hi.y) << 16);
      f.u.w = (unsigned int)f2h(sc * hi.z) | ((unsigned int)f2h(sc * hi.w) << 16);
      Bf[g][kh] = f.v;
    }
  }

  HU bex[4];
  #pragma unroll
  for (int g = 0; g < 4; ++g) {
    const float sc = (g == 2) ? (-2.0f * L2E) : -L2E;
    const float gu = sc * ws[S_GU + g * 64 + d];
    const float gc = sc * ws[S_GC + g * 64 + d];
    const float g0 = sc * ws[S_G0 + g * 64 + d];
    bex[g].u.x = (q == 0) ? ((unsigned int)f2h(gu) | ((unsigned int)f2h(gc) << 16)) : 0u;
    bex[g].u.y = (q == 0) ? (unsigned int)f2h(g0) : 0u;   // elem2 = G0, elem3 = 0
    bex[g].u.z = 0u; bex[g].u.w = 0u;
  }
  const float WO = w_out[br * 64 + d];
  const float BO = b_out[0];
  __syncthreads();  // pq staged

  // cell state carried SCALED: cst = -2*log2e * c  (so ed = 2^cst directly)
  const float K  = -2.0f * L2E;
  const float NK = 2.0f * L2E;
  f32x4 cst[2];
  float pr[2][4];
  #pragma unroll
  for (int mi = 0; mi < 2; ++mi) cst[mi] = (f32x4){0.f, 0.f, 0.f, 0.f};
  const f32x4 z4 = (f32x4){0.f, 0.f, 0.f, 0.f};

  #pragma unroll 1
  for (int t = 0; t < NTT; ++t) {
    const unsigned short* hr = smem + ((t + 1) & 1) * (32 * RS2);
    unsigned short* hw = smem + (t & 1) * (32 * RS2);
    const bool last = (t == NTT - 1);
    #pragma unroll
    for (int mi = 0; mi < 2; ++mi) {
      HU ae;
      ae.u.x = (q == 0) ? pq_sh[t][mi * 16 + l15] : 0u;
      ae.u.y = (q == 0) ? 0x3C00u : 0u;   // elem2 = 1.0h
      ae.u.z = 0u; ae.u.w = 0u;
      f32x4 aI = __builtin_amdgcn_mfma_f32_16x16x32_f16(ae.v, bex[0].v, z4, 0, 0, 0);
      f32x4 aF = __builtin_amdgcn_mfma_f32_16x16x32_f16(ae.v, bex[1].v, z4, 0, 0, 0);
      f32x4 aG = __builtin_amdgcn_mfma_f32_16x16x32_f16(ae.v, bex[2].v, z4, 0, 0, 0);
      f32x4 aO = __builtin_amdgcn_mfma_f32_16x16x32_f16(ae.v, bex[3].v, z4, 0, 0, 0);
      if (t > 0) {
        #pragma unroll
        for (int kh = 0; kh < 2; ++kh) {
          const f16x8 Ah = ldsH(&hr[(mi * 16 + l15) * RS2 + kh * 32 + q * 8]);
          aI = __builtin_amdgcn_mfma_f32_16x16x32_f16(Ah, Bf[0][kh], aI, 0, 0, 0);
          aF = __builtin_amdgcn_mfma_f32_16x16x32_f16(Ah, Bf[1][kh], aF, 0, 0, 0);
          aG = __builtin_amdgcn_mfma_f32_16x16x32_f16(Ah, Bf[2][kh], aG, 0, 0, 0);
          aO = __builtin_amdgcn_mfma_f32_16x16x32_f16(Ah, Bf[3][kh], aO, 0, 0, 0);
        }
      }
      #pragma unroll
      for (int r = 0; r < 4; ++r) {
        const float cs = cst[mi][r];
        const float ea = __builtin_amdgcn_exp2f(aI[r]);
        const float eb = __builtin_amdgcn_exp2f(aG[r]);
        const float ef = __builtin_amdgcn_exp2f(aF[r]);
        const float A  = 1.0f + ea, Bb = 1.0f + eb, Fd = 1.0f + ef;
        const float P  = A * Bb;
        const float tK = fmaf(eb, NK, K);                  // K*(1-eb)
        const float numer = fmaf(cs, P, tK * Fd);
        const float cns = numer * __builtin_amdgcn_rcpf(Fd * P);  // K*c_new
        cst[mi][r] = cns;
        const float ec = __builtin_amdgcn_exp2f(aO[r]);
        const float ed = __builtin_amdgcn_exp2f(cns);
        const float h = (1.0f - ed) *
            __builtin_amdgcn_rcpf((1.0f + ec) * (1.0f + ed));    // sig(o)*tanh(c)
        if (!last) {
          hw[(mi * 16 + q * 4 + r) * RS2 + d] = f2h(h);
        } else {
          pr[mi][r] = h * WO;
        }
      }
    }
    __syncthreads();
  }
  float* fbuf = (float*)smem;
  #pragma unroll
  for (int mi = 0; mi < 2; ++mi)
    #pragma unroll
    for (int r = 0; r < 4; ++r) {
      float v = pr[mi][r];
      v += __shfl_xor(v, 1);
      v += __shfl_xor(v, 2);
      v += __shfl_xor(v, 4);
      v += __shfl_xor(v, 8);
      if (l15 == 0) fbuf[w * 32 + mi * 16 + q * 4 + r] = v;
    }
  __syncthreads();
  if (tid < 32) {
    const int v = v0 + tid;
    if (v < NV) {
      const float s = fbuf[tid] + fbuf[32 + tid] + fbuf[64 + tid] + fbuf[96 + tid];
      atomicAdd(&out[b * NV + v], s + ((br == 0) ? BO : 0.0f));
    }
  }
}

// fallback transpose (non-batched workspace path only)
__global__ void k_trans2(const float* __restrict__ s0, const float* __restrict__ s1,
                         float* __restrict__ xT, int xtS) {
  __shared__ float tile[128][49];
  const float* seq = blockIdx.y ? s1 : s0;
  float* o = xT + (size_t)blockIdx.y * xtS;
  const int v0 = blockIdx.x * 128;
  const int tid = threadIdx.x;
  for (int i = tid; i < 128 * NSEQ; i += 256) {
    const int n = i / 128, vl = i % 128;
    const int v = v0 + vl;
    tile[vl][n] = (v < NV) ? seq[n * NV + v] : 0.0f;
  }
  __syncthreads();
  for (int i = tid; i < 128 * NSEQ; i += 256) {
    const int vl = i / NSEQ, n = i % NSEQ;
    const int v = v0 + vl;
    if (v < NV) o[v * NSEQ + n] = tile[vl][n];
  }
}

extern "C" void kernel_launch(void* const* d_in, const int* in_sizes, int n_in,
                              void* d_out, int out_size, void* d_ws, size_t ws_size,
                              hipStream_t stream) {
  const float* tend   = (const float*)d_in[0];
  const float* peri   = (const float*)d_in[1];
  const int*   edges  = (const int*)d_in[2];
  const float* w1     = (const float*)d_in[3];
  const float* b1     = (const float*)d_in[4];
  const float* w2     = (const float*)d_in[5];
  const float* b2     = (const float*)d_in[6];
  const float* attn_w = (const float*)d_in[7];
  const float* attn_a = (const float*)d_in[8];
  const float* w_ih   = (const float*)d_in[9];
  const float* w_hh   = (const float*)d_in[10];
  const float* b_ih   = (const float*)d_in[11];
  const float* b_hh   = (const float*)d_in[12];
  const float* w_out  = (const float*)d_in[13];
  const float* b_out  = (const float*)d_in[14];
  float* out = (float*)d_out;
  float* ws  = (float*)d_ws;
  int*   iws = (int*)d_ws;
  int* cnt = iws + I_CNT;
  int* cur = iws + I_CUR;
  int* off = iws + I_OFF;
  int* sed = iws + I_SLOT;
  unsigned int* pqw = (unsigned int*)(ws + F_PQ);

  const size_t need2 = ((size_t)F_DYN + 2 * (XT_SZ + AGG_SZ + YZ_SZ)) * 4;
  const bool batched = ws_size >= need2;
  const int nb = batched ? 2 : 1;
  float* XT  = ws + F_DYN;
  float* AGG = XT + (size_t)nb * XT_SZ;
  float* YZ  = AGG + (size_t)nb * AGG_SZ;
  float* Bm   = YZ;                 // batched: B matrix in dead YZ region (3 MB)
  float* AGG2 = YZ + B_SZ;          // batched: agg2 output (2 branches)

  const int g_eagg = (NH * NE * 12 * 8) / 256;   // 576
  const int g_vg   = (NH * NV * 12 + 255) / 256;
  const int g_attn = (NV * 12 + 255) / 256;

  if (batched) {
    const int nz = NZERO + B_SZ;
    const int zblk = (nz + 255) / 256;
    k_init<<<1 + zblk + 2 * TRB, 256, 0, stream>>>(
        w1, b1, w2, b2, attn_w, attn_a, w_ih, b_ih, b_hh, ws, cnt, out,
        tend, peri, XT, XT_SZ, Bm, nz, zblk);
    k_count<<<(NH * NE * NS) / 256, 256, 0, stream>>>(edges, cnt);
    k_scan<<<NH, 1024, 0, stream>>>(cnt, off, ws + F_INV, ws + F_M);
    k_fe1<<<192 + 2 * g_eagg, 256, 0, stream>>>(edges, off, cur, sed, XT, XT_SZ, AGG, AGG_SZ);
    k_bmat<<<(NH * NV + 255) / 256, 256, 0, stream>>>(cnt, off, sed, ws + F_INV, Bm);
    k_gemm<<<dim3(g_eagg, 2), 256, 0, stream>>>(Bm, AGG, AGG_SZ, AGG2, AGG_SZ);
    k_vgattn<<<dim3(g_attn, 2), 256, 0, stream>>>(cnt, off, sed, AGG2, AGG_SZ,
                                                  ws + F_INV, ws + F_M, ws, pqw, 0);
  } else {
    k_init<<<1 + ZBLK, 256, 0, stream>>>(
        w1, b1, w2, b2, attn_w, attn_a, w_ih, b_ih, b_hh, ws, cnt, out,
        tend, peri, XT, XT_SZ, XT, NZERO, ZBLK);
    k_count<<<(NH * NE * NS) / 256, 256, 0, stream>>>(edges, cnt);
    k_scan<<<NH, 1024, 0, stream>>>(cnt, off, ws + F_INV, ws + F_M);
    k_fill<<<(NH * NE * NS) / 256, 256, 0, stream>>>(edges, off, cur, sed);
    for (int br = 0; br < 2; ++br) {
      const float* seq = br ? peri : tend;
      k_trans2<<<dim3(TRB, 1), 256, 0, stream>>>(seq, seq, XT, 0);
      k_eagg1<<<dim3(g_eagg, 1), 256, 0, stream>>>(edges, XT, 0, AGG, 0);
      k_vg<<<dim3(g_vg, 1), 256, 0, stream>>>(cnt, off, sed, AGG, 0, YZ, 0);
      k_eagg2<<<dim3(g_eagg, 1), 256, 0, stream>>>(edges, YZ, 0, ws + F_INV, AGG, 0);
      k_vgattn<<<dim3(g_attn, 1), 256, 0, stream>>>(cnt, off, sed, AGG, 0,
                                                    ws + F_INV, ws + F_M, ws, pqw, br);
    }
  }
  k_lstm2<<<NVT * NB * 2, 256, 0, stream>>>(w_hh, ws, pqw, w_out, b_out, out);
}

// Round 15
// 222.069 us; speedup vs baseline: 1.3078x; 1.3078x over previous
//
#include <hip/hip_runtime.h>

#define NV 10000
#define NB 4
#define NTT 12
#define NSEQ 48
#define NH 3
#define NE 512
#define NS 32
#define ND 64
#define NVT 313   // ceil(NV/32) 32-seq tiles

// ---- fixed workspace layout (element indices; float and int regions share the base) ----
#define S_U   0
#define S_C1  64
#define S_V1  128
#define S_V2  192
#define S_SC  256
#define S_GU  272
#define S_GC  528
#define S_G0  784
#define F_INV 1040
#define F_M   (F_INV + NH*NV)            // 31040
#define F_PQ  (F_M + NH*NV)              // 61040  (holds 2*NV*NSEQ u32 packed pq)
#define F_HT  (F_PQ + 4*NV*NSEQ)         // (spare)
#define I_CNT (F_HT + 2*NB*NV)           // 2061040
#define I_CUR (I_CNT + NH*NV)
#define I_OFF (I_CUR + NH*NV)
#define I_SLOT (I_OFF + NH*NV)
#define F_DYN (I_SLOT + NH*NE*NS)        // 2200192
#define XT_SZ  (NV*NSEQ)                 // 480000
#define AGG_SZ (NH*NE*NSEQ)              // 73728
#define YZ_SZ  (NH*NV*NSEQ)              // 1440000

#define NZERO (2*NH*NV + NB*NV)          // ints zeroed (cnt+cur) + floats zeroed (out)
#define ZBLK  ((NZERO + 255) / 256)      // 391 zero blocks
#define TRB   ((NV + 127) / 128)         // 79 transpose tiles per branch

#define L2E 1.442695040888963f           // log2(e)

typedef __attribute__((ext_vector_type(8))) _Float16 f16x8;
typedef __attribute__((ext_vector_type(4))) float f32x4;

__device__ __forceinline__ unsigned short f2h(float x) {
  union { _Float16 h; unsigned short u; } c;
  c.h = (_Float16)x;   // v_cvt_f16_f32, RNE
  return c.u;
}
__device__ __forceinline__ f16x8 ldsH(const unsigned short* p) {
  union { uint4 u; f16x8 v; } x;
  x.u = *(const uint4*)p;
  return x.v;
}

// ---------------- merged: weight precompute (block 0) + zeroing + input transpose ----------------
__global__ void k_init(const float* __restrict__ w1, const float* __restrict__ b1,
                       const float* __restrict__ w2, const float* __restrict__ b2,
                       const float* __restrict__ attn_w, const float* __restrict__ attn_a,
                       const float* __restrict__ w_ih, const float* __restrict__ b_ih,
                       const float* __restrict__ b_hh, float* __restrict__ ws,
                       int* __restrict__ cnt, float* __restrict__ out,
                       const float* __restrict__ s0, const float* __restrict__ s1,
                       float* __restrict__ xT, int xtS) {
  const int tid = threadIdx.x;
  if (blockIdx.x > ZBLK) {
    // transpose seq [48][NV] -> xT [NV][48], 128-vertex tiles
    __shared__ float tile[128][49];
    const int bx = blockIdx.x - 1 - ZBLK;
    const int brn = bx / TRB;
    const int v0 = (bx % TRB) * 128;
    const float* seq = brn ? s1 : s0;
    float* o = xT + (size_t)brn * xtS;
    for (int i = tid; i < 128 * NSEQ; i += 256) {
      const int n = i / 128, vl = i % 128;
      const int v = v0 + vl;
      tile[vl][n] = (v < NV) ? seq[n * NV + v] : 0.0f;
    }
    __syncthreads();
    for (int i = tid; i < 128 * NSEQ; i += 256) {
      const int vl = i / NSEQ, n = i % NSEQ;
      const int v = v0 + vl;
      if (v < NV) o[v * NSEQ + n] = tile[vl][n];
    }
    return;
  }
  if (blockIdx.x != 0) {
    const int g = (blockIdx.x - 1) * 256 + tid;
    if (g < 2 * NH * NV) cnt[g] = 0;
    else if (g < NZERO) out[g - 2 * NH * NV] = 0.0f;
    return;
  }
  __shared__ float u_s[64], c1_s[64];
  if (tid < 64) {
    float v1 = 0.f, v2 = 0.f, u = 0.f, c1 = 0.f;
    for (int d = 0; d < 64; ++d) {
      const float aw = attn_w[tid * 64 + d];
      v1 += aw * attn_a[d];
      v2 += aw * attn_a[64 + d];
      const float w2v = w2[d * 64 + tid];
      u  += w1[d] * w2v;
      c1 += b1[d] * w2v;
    }
    ws[S_U + tid] = u;  ws[S_C1 + tid] = c1;
    ws[S_V1 + tid] = v1; ws[S_V2 + tid] = v2;
    u_s[tid] = u; c1_s[tid] = c1;
  }
  __syncthreads();
  if (tid == 0) {
    float al = 0.f, be = 0.f, ga = 0.f, de = 0.f, ep = 0.f;
    for (int d = 0; d < 64; ++d) {
      const float v1 = ws[S_V1 + d], v2 = ws[S_V2 + d];
      al += u_s[d] * v1;  be += c1_s[d] * v1;
      ga += u_s[d] * v2;  de += c1_s[d] * v2;
      ep += b2[d] * (v1 + v2);
    }
    ws[S_SC + 0] = al; ws[S_SC + 1] = be; ws[S_SC + 2] = ga;
    ws[S_SC + 3] = de; ws[S_SC + 4] = ep;
  }
  {
    const int j = tid;  // 256 threads exactly
    float gu = 0.f, gc = 0.f, g0 = 0.f;
    for (int d = 0; d < 64; ++d) {
      const float w = w_ih[j * 64 + d];
      gu += w * u_s[d]; gc += w * c1_s[d]; g0 += w * b2[d];
    }
    ws[S_GU + j] = gu; ws[S_GC + j] = gc;
    ws[S_G0 + j] = g0 + b_ih[j] + b_hh[j];
  }
}

// ---------------- graph structure ----------------
__global__ void k_count(const int* __restrict__ edges, int* __restrict__ counts) {
  const int g = blockIdx.x * 256 + threadIdx.x;
  if (g >= NH * NE * NS) return;
  const int h = g >> 14;
  atomicAdd(&counts[h * NV + edges[g]], 1);
}

__global__ void k_scan(const int* __restrict__ counts, int* __restrict__ offs,
                       float* __restrict__ invdeg, float* __restrict__ mvec) {
  const int h = blockIdx.x;
  const int tid = threadIdx.x;  // 1024 threads
  const int base = h * NV;
  const int CH = 10;
  int local[10];
  int run = 0;
  for (int i = 0; i < CH; ++i) {
    const int v = tid * CH + i;
    const int c = (v < NV) ? counts[base + v] : 0;
    local[i] = run; run += c;
  }
  __shared__ int sd[1024];
  sd[tid] = run;
  __syncthreads();
  int acc = run;
  for (int off = 1; off < 1024; off <<= 1) {
    const int t = (tid >= off) ? sd[tid - off] : 0;
    __syncthreads();
    acc += t; sd[tid] = acc;
    __syncthreads();
  }
  const int excl = acc - run;
  for (int i = 0; i < CH; ++i) {
    const int v = tid * CH + i;
    if (v < NV) {
      offs[base + v] = excl + local[i];
      const int c = counts[base + v];
      invdeg[base + v] = 1.0f / (float)((c > 0) ? c : 1);
      mvec[base + v] = (c > 0) ? 1.0f : 0.0f;
    }
  }
}

// ---- fused: CSR fill (blocks [0,192)) || eagg1 both branches (blocks [192,1344)) ----
// fill depends on scan; eagg1 depends only on k_init's XT -> both inputs ready here,
// and the two jobs are mutually independent (fill writes sed; eagg1 reads edges/XT,
// writes AGG). One launch instead of two; fill's atomics hide under eagg1's gathers.
__global__ void k_fe1(const int* __restrict__ edges, const int* __restrict__ offs,
                      int* __restrict__ cursor, int* __restrict__ slot_edge,
                      const float* __restrict__ xT, int xtS,
                      float* __restrict__ agg, int aggS) {
  const int tid = threadIdx.x;
  if (blockIdx.x < 192) {
    const int g = blockIdx.x * 256 + tid;   // == NH*NE*NS exactly at 192*256
    const int h = g >> 14;
    const int e = (g >> 5) & (NE - 1);
    const int v = edges[g];
    const int pos = atomicAdd(&cursor[h * NV + v], 1);
    slot_edge[h * NE * NS + offs[h * NV + v] + pos] = e;
    return;
  }
  const int job = blockIdx.x - 192;         // 0..1151
  const int brn = job / 576;
  const int g = (job % 576) * 256 + tid;    // < NH*NE*12*8 exactly
  const float* x = xT + (size_t)brn * xtS;
  float* a = agg + (size_t)brn * aggS;
  const int sub = g & 7;
  const int o = g >> 3;
  const int n0 = (o % 12) * 4;
  const int e = (o / 12) % NE;
  const int h = o / (12 * NE);
  const int* ep = edges + (h * NE + e) * NS + sub * 4;
  float4 acc = make_float4(0.f, 0.f, 0.f, 0.f);
  #pragma unroll
  for (int s = 0; s < 4; ++s) {
    const float4 t = *(const float4*)&x[ep[s] * NSEQ + n0];
    acc.x += t.x; acc.y += t.y; acc.z += t.z; acc.w += t.w;
  }
  #pragma unroll
  for (int m = 1; m < 8; m <<= 1) {
    acc.x += __shfl_xor(acc.x, m);
    acc.y += __shfl_xor(acc.y, m);
    acc.z += __shfl_xor(acc.z, m);
    acc.w += __shfl_xor(acc.w, m);
  }
  if (sub == 0) {
    acc.x *= (1.0f / NS); acc.y *= (1.0f / NS); acc.z *= (1.0f / NS); acc.w *= (1.0f / NS);
    *(float4*)&a[(h * NE + e) * NSEQ + n0] = acc;
  }
}

// separate fill / eagg1 (non-batched fallback path only)
__global__ void k_fill(const int* __restrict__ edges, const int* __restrict__ offs,
                       int* __restrict__ cursor, int* __restrict__ slot_edge) {
  const int g = blockIdx.x * 256 + threadIdx.x;
  if (g >= NH * NE * NS) return;
  const int h = g >> 14;
  const int e = (g >> 5) & (NE - 1);
  const int v = edges[g];
  const int pos = atomicAdd(&cursor[h * NV + v], 1);
  slot_edge[h * NE * NS + offs[h * NV + v] + pos] = e;
}

__global__ void k_eagg1(const int* __restrict__ edges, const float* __restrict__ xT,
                        int xtS, float* __restrict__ agg, int aggS) {
  const int g = blockIdx.x * 256 + threadIdx.x;
  if (g >= NH * NE * 12 * 8) return;
  const float* x = xT + (size_t)blockIdx.y * xtS;
  float* a = agg + (size_t)blockIdx.y * aggS;
  const int sub = g & 7;
  const int o = g >> 3;
  const int n0 = (o % 12) * 4;
  const int e = (o / 12) % NE;
  const int h = o / (12 * NE);
  const int* ep = edges + (h * NE + e) * NS + sub * 4;
  float4 acc = make_float4(0.f, 0.f, 0.f, 0.f);
  #pragma unroll
  for (int s = 0; s < 4; ++s) {
    const float4 t = *(const float4*)&x[ep[s] * NSEQ + n0];
    acc.x += t.x; acc.y += t.y; acc.z += t.z; acc.w += t.w;
  }
  #pragma unroll
  for (int m = 1; m < 8; m <<= 1) {
    acc.x += __shfl_xor(acc.x, m);
    acc.y += __shfl_xor(acc.y, m);
    acc.z += __shfl_xor(acc.z, m);
    acc.w += __shfl_xor(acc.w, m);
  }
  if (sub == 0) {
    acc.x *= (1.0f / NS); acc.y *= (1.0f / NS); acc.z *= (1.0f / NS); acc.w *= (1.0f / NS);
    *(float4*)&a[(h * NE + e) * NSEQ + n0] = acc;
  }
}

__global__ void k_eagg2(const int* __restrict__ edges, const float* __restrict__ ysum,
                        int yS, const float* __restrict__ invdeg,
                        float* __restrict__ agg, int aggS) {
  const int g = blockIdx.x * 256 + threadIdx.x;
  if (g >= NH * NE * 12 * 8) return;
  const float* y = ysum + (size_t)blockIdx.y * yS;
  float* a = agg + (size_t)blockIdx.y * aggS;
  const int sub = g & 7;
  const int o = g >> 3;
  const int n0 = (o % 12) * 4;
  const int e = (o / 12) % NE;
  const int h = o / (12 * NE);
  const int* ep = edges + (h * NE + e) * NS + sub * 4;
  float4 acc = make_float4(0.f, 0.f, 0.f, 0.f);
  #pragma unroll
  for (int s = 0; s < 4; ++s) {
    const int v = ep[s];
    const float iv = invdeg[h * NV + v];
    const float4 t = *(const float4*)&y[(h * NV + v) * NSEQ + n0];
    acc.x += t.x * iv; acc.y += t.y * iv; acc.z += t.z * iv; acc.w += t.w * iv;
  }
  #pragma unroll
  for (int m = 1; m < 8; m <<= 1) {
    acc.x += __shfl_xor(acc.x, m);
    acc.y += __shfl_xor(acc.y, m);
    acc.z += __shfl_xor(acc.z, m);
    acc.w += __shfl_xor(acc.w, m);
  }
  if (sub == 0) {
    acc.x *= (1.0f / NS); acc.y *= (1.0f / NS); acc.z *= (1.0f / NS); acc.w *= (1.0f / NS);
    *(float4*)&a[(h * NE + e) * NSEQ + n0] = acc;
  }
}

// stage-1 vertex gather (unnormalized; invdeg folded downstream in eagg2)
__global__ void k_vg(const int* __restrict__ counts, const int* __restrict__ offs,
                     const int* __restrict__ slot_edge, const float* __restrict__ agg,
                     int aggS, float* __restrict__ outv, int outS) {
  const int g = blockIdx.x * 256 + threadIdx.x;
  if (g >= NH * NV * 12) return;
  const float* a = agg + (size_t)blockIdx.y * aggS;
  float* o = outv + (size_t)blockIdx.y * outS;
  const int n0 = (g % 12) * 4;
  const int v = (g / 12) % NV;
  const int h = g / (12 * NV);
  const int beg = offs[h * NV + v];
  const int cnt = counts[h * NV + v];
  const int* se = slot_edge + h * NE * NS;
  float4 acc = make_float4(0.f, 0.f, 0.f, 0.f);
  for (int i = 0; i < cnt; ++i) {
    const int e = se[beg + i];
    const float4 t = *(const float4*)&a[(h * NE + e) * NSEQ + n0];
    acc.x += t.x; acc.y += t.y; acc.z += t.z; acc.w += t.w;
  }
  *(float4*)&o[(h * NV + v) * NSEQ + n0] = acc;
}

// ---- fused stage-2 vertex gather + attention; writes packed f16 (p,q) pairs ----
__global__ void k_vgattn(const int* __restrict__ counts, const int* __restrict__ offs,
                         const int* __restrict__ slot_edge, const float* __restrict__ agg,
                         int aggS, const float* __restrict__ invdeg,
                         const float* __restrict__ mvec, const float* __restrict__ ws,
                         unsigned int* __restrict__ pq, int br0) {
  const int g = blockIdx.x * 256 + threadIdx.x;
  if (g >= NV * 12) return;
  const int bi = blockIdx.y;
  const float* a = agg + (size_t)bi * aggS;
  unsigned int* pbuf = pq + (size_t)(bi + br0) * NV * NSEQ;
  const int n0 = (g % 12) * 4;
  const int v = g / 12;
  const float al = ws[S_SC + 0], be = ws[S_SC + 1], ga = ws[S_SC + 2],
              de = ws[S_SC + 3], ep = ws[S_SC + 4];
  union { float4 v4; float f[4]; } zh[3];
  float mh[3];
  #pragma unroll
  for (int h = 0; h < NH; ++h) {
    const int beg = offs[h * NV + v];
    const int cnt = counts[h * NV + v];
    const int* se = slot_edge + h * NE * NS;
    float4 acc = make_float4(0.f, 0.f, 0.f, 0.f);
    for (int i = 0; i < cnt; ++i) {
      const int e = se[beg + i];
      const float4 t = *(const float4*)&a[(h * NE + e) * NSEQ + n0];
      acc.x += t.x; acc.y += t.y; acc.z += t.z; acc.w += t.w;
    }
    const float iv = invdeg[h * NV + v];
    zh[h].v4 = make_float4(acc.x * iv, acc.y * iv, acc.z * iv, acc.w * iv);
    mh[h] = mvec[h * NV + v];
  }
  const float mb = (mh[0] + mh[1] + mh[2]) * (1.f / 3.f);
  uint4 o4;
  unsigned int* op = (unsigned int*)&o4;
  #pragma unroll
  for (int j = 0; j < 4; ++j) {
    const float z0 = zh[0].f[j], z1 = zh[1].f[j], z2 = zh[2].f[j];
    const float zb = (z0 + z1 + z2) * (1.f / 3.f);
    float sc[3];
    const float zt[3] = {z0, z1, z2};
    #pragma unroll
    for (int h = 0; h < NH; ++h) {
      const float s = al * zt[h] + be * mh[h] + ga * zb + de * mb + ep;
      sc[h] = (s > 0.f) ? s : 0.2f * s;
    }
    const float mx = fmaxf(sc[0], fmaxf(sc[1], sc[2]));
    const float e0 = __expf(sc[0] - mx), e1 = __expf(sc[1] - mx), e2 = __expf(sc[2] - mx);
    const float inv = 1.0f / (e0 + e1 + e2);
    const float pv = (e0 * z0 + e1 * z1 + e2 * z2) * inv;
    const float qv = (e0 * mh[0] + e1 * mh[1] + e2 * mh[2]) * inv;
    op[j] = (unsigned int)f2h(pv) | ((unsigned int)f2h(qv) << 16);
  }
  *(uint4*)&pbuf[v * NSEQ + n0] = o4;
}

// ---------------- MFMA LSTM (R11-verified; unchanged) ----------------
#define RS2 72  // h row stride (ushorts): 64 + 8 pad, 144 B (16B-aligned rows)
__launch_bounds__(256, 4)
__global__ void k_lstm2(const float* __restrict__ w_hh, const float* __restrict__ ws,
                        const unsigned int* __restrict__ pqbase,
                        const float* __restrict__ w_out, const float* __restrict__ b_out,
                        float* __restrict__ out) {
  __shared__ __align__(16) unsigned short smem[2 * 32 * RS2];  // 9216 B h double-buffer
  __shared__ unsigned int pq_sh[NTT][32];                      // packed (p,q) f16, 1536 B
  const int tid = threadIdx.x;
  const int w = tid >> 6, lane = tid & 63, q = lane >> 4, l15 = lane & 15;
  const int bid = blockIdx.x;
  const int vt = bid % NVT;
  const int b  = (bid / NVT) % NB;
  const int br = bid / (NVT * NB);
  const int v0 = vt * 32;
  const int d = w * 16 + l15;  // this lane's gate-dim within [0,64)

  union HU { uint4 u; f16x8 v; };

  // stage packed pq for all 12 steps (uint4 over t): 96 uint4
  const unsigned int* pqb = pqbase + (size_t)br * NV * NSEQ;
  if (tid < 96) {
    const int s = tid / 3, f4 = tid % 3;
    const int v = v0 + s;
    uint4 val = make_uint4(0u, 0u, 0u, 0u);
    if (v < NV) val = *(const uint4*)&pqb[v * NSEQ + b * NTT + f4 * 4];
    pq_sh[f4 * 4 + 0][s] = val.x; pq_sh[f4 * 4 + 1][s] = val.y;
    pq_sh[f4 * 4 + 2][s] = val.z; pq_sh[f4 * 4 + 3][s] = val.w;
  }

  // B fragments direct from global; prescale I/F/O by -log2e, G by -2*log2e.
  f16x8 Bf[4][2];
  #pragma unroll
  for (int g = 0; g < 4; ++g) {
    const float sc = (g == 2) ? (-2.0f * L2E) : -L2E;
    #pragma unroll
    for (int kh = 0; kh < 2; ++kh) {
      const float* wp = w_hh + (g * 64 + d) * 64 + kh * 32 + q * 8;
      const float4 lo = *(const float4*)wp;
      const float4 hi = *(const float4*)(wp + 4);
      HU f;
      f.u.x = (unsigned int)f2h(sc * lo.x) | ((unsigned int)f2h(sc * lo.y) << 16);
      f.u.y = (unsigned int)f2h(sc * lo.z) | ((unsigned int)f2h(sc * lo.w) << 16);
      f.u.z = (unsigned int)f2h(sc * hi.x) | ((unsigned int)f2h(sc * hi.y) << 16);
      f.u.w = (unsigned int)f2h(sc * hi.z) | ((unsigned int)f2h(sc * hi.w) << 16);
      Bf[g][kh] = f.v;
    }
  }

  HU bex[4];
  #pragma unroll
  for (int g = 0; g < 4; ++g) {
    const float sc = (g == 2) ? (-2.0f * L2E) : -L2E;
    const float gu = sc * ws[S_GU + g * 64 + d];
    const float gc = sc * ws[S_GC + g * 64 + d];
    const float g0 = sc * ws[S_G0 + g * 64 + d];
    bex[g].u.x = (q == 0) ? ((unsigned int)f2h(gu) | ((unsigned int)f2h(gc) << 16)) : 0u;
    bex[g].u.y = (q == 0) ? (unsigned int)f2h(g0) : 0u;   // elem2 = G0, elem3 = 0
    bex[g].u.z = 0u; bex[g].u.w = 0u;
  }
  const float WO = w_out[br * 64 + d];
  const float BO = b_out[0];
  __syncthreads();  // pq staged

  // cell state carried SCALED: cst = -2*log2e * c  (so ed = 2^cst directly)
  const float K  = -2.0f * L2E;
  const float NK = 2.0f * L2E;
  f32x4 cst[2];
  float pr[2][4];
  #pragma unroll
  for (int mi = 0; mi < 2; ++mi) cst[mi] = (f32x4){0.f, 0.f, 0.f, 0.f};
  const f32x4 z4 = (f32x4){0.f, 0.f, 0.f, 0.f};

  #pragma unroll 1
  for (int t = 0; t < NTT; ++t) {
    const unsigned short* hr = smem + ((t + 1) & 1) * (32 * RS2);
    unsigned short* hw = smem + (t & 1) * (32 * RS2);
    const bool last = (t == NTT - 1);
    #pragma unroll
    for (int mi = 0; mi < 2; ++mi) {
      HU ae;
      ae.u.x = (q == 0) ? pq_sh[t][mi * 16 + l15] : 0u;
      ae.u.y = (q == 0) ? 0x3C00u : 0u;   // elem2 = 1.0h
      ae.u.z = 0u; ae.u.w = 0u;
      f32x4 aI = __builtin_amdgcn_mfma_f32_16x16x32_f16(ae.v, bex[0].v, z4, 0, 0, 0);
      f32x4 aF = __builtin_amdgcn_mfma_f32_16x16x32_f16(ae.v, bex[1].v, z4, 0, 0, 0);
      f32x4 aG = __builtin_amdgcn_mfma_f32_16x16x32_f16(ae.v, bex[2].v, z4, 0, 0, 0);
      f32x4 aO = __builtin_amdgcn_mfma_f32_16x16x32_f16(ae.v, bex[3].v, z4, 0, 0, 0);
      if (t > 0) {
        #pragma unroll
        for (int kh = 0; kh < 2; ++kh) {
          const f16x8 Ah = ldsH(&hr[(mi * 16 + l15) * RS2 + kh * 32 + q * 8]);
          aI = __builtin_amdgcn_mfma_f32_16x16x32_f16(Ah, Bf[0][kh], aI, 0, 0, 0);
          aF = __builtin_amdgcn_mfma_f32_16x16x32_f16(Ah, Bf[1][kh], aF, 0, 0, 0);
          aG = __builtin_amdgcn_mfma_f32_16x16x32_f16(Ah, Bf[2][kh], aG, 0, 0, 0);
          aO = __builtin_amdgcn_mfma_f32_16x16x32_f16(Ah, Bf[3][kh], aO, 0, 0, 0);
        }
      }
      #pragma unroll
      for (int r = 0; r < 4; ++r) {
        const float cs = cst[mi][r];
        const float ea = __builtin_amdgcn_exp2f(aI[r]);
        const float eb = __builtin_amdgcn_exp2f(aG[r]);
        const float ef = __builtin_amdgcn_exp2f(aF[r]);
        const float A  = 1.0f + ea, Bb = 1.0f + eb, Fd = 1.0f + ef;
        const float P  = A * Bb;
        const float tK = fmaf(eb, NK, K);                  // K*(1-eb)
        const float numer = fmaf(cs, P, tK * Fd);
        const float cns = numer * __builtin_amdgcn_rcpf(Fd * P);  // K*c_new
        cst[mi][r] = cns;
        const float ec = __builtin_amdgcn_exp2f(aO[r]);
        const float ed = __builtin_amdgcn_exp2f(cns);
        const float h = (1.0f - ed) *
            __builtin_amdgcn_rcpf((1.0f + ec) * (1.0f + ed));    // sig(o)*tanh(c)
        if (!last) {
          hw[(mi * 16 + q * 4 + r) * RS2 + d] = f2h(h);
        } else {
          pr[mi][r] = h * WO;
        }
      }
    }
    __syncthreads();
  }
  float* fbuf = (float*)smem;
  #pragma unroll
  for (int mi = 0; mi < 2; ++mi)
    #pragma unroll
    for (int r = 0; r < 4; ++r) {
      float v = pr[mi][r];
      v += __shfl_xor(v, 1);
      v += __shfl_xor(v, 2);
      v += __shfl_xor(v, 4);
      v += __shfl_xor(v, 8);
      if (l15 == 0) fbuf[w * 32 + mi * 16 + q * 4 + r] = v;
    }
  __syncthreads();
  if (tid < 32) {
    const int v = v0 + tid;
    if (v < NV) {
      const float s = fbuf[tid] + fbuf[32 + tid] + fbuf[64 + tid] + fbuf[96 + tid];
      atomicAdd(&out[b * NV + v], s + ((br == 0) ? BO : 0.0f));
    }
  }
}

// fallback transpose (non-batched workspace path only)
__global__ void k_trans2(const float* __restrict__ s0, const float* __restrict__ s1,
                         float* __restrict__ xT, int xtS) {
  __shared__ float tile[128][49];
  const float* seq = blockIdx.y ? s1 : s0;
  float* o = xT + (size_t)blockIdx.y * xtS;
  const int v0 = blockIdx.x * 128;
  const int tid = threadIdx.x;
  for (int i = tid; i < 128 * NSEQ; i += 256) {
    const int n = i / 128, vl = i % 128;
    const int v = v0 + vl;
    tile[vl][n] = (v < NV) ? seq[n * NV + v] : 0.0f;
  }
  __syncthreads();
  for (int i = tid; i < 128 * NSEQ; i += 256) {
    const int vl = i / NSEQ, n = i % NSEQ;
    const int v = v0 + vl;
    if (v < NV) o[v * NSEQ + n] = tile[vl][n];
  }
}

extern "C" void kernel_launch(void* const* d_in, const int* in_sizes, int n_in,
                              void* d_out, int out_size, void* d_ws, size_t ws_size,
                              hipStream_t stream) {
  const float* tend   = (const float*)d_in[0];
  const float* peri   = (const float*)d_in[1];
  const int*   edges  = (const int*)d_in[2];
  const float* w1     = (const float*)d_in[3];
  const float* b1     = (const float*)d_in[4];
  const float* w2     = (const float*)d_in[5];
  const float* b2     = (const float*)d_in[6];
  const float* attn_w = (const float*)d_in[7];
  const float* attn_a = (const float*)d_in[8];
  const float* w_ih   = (const float*)d_in[9];
  const float* w_hh   = (const float*)d_in[10];
  const float* b_ih   = (const float*)d_in[11];
  const float* b_hh   = (const float*)d_in[12];
  const float* w_out  = (const float*)d_in[13];
  const float* b_out  = (const float*)d_in[14];
  float* out = (float*)d_out;
  float* ws  = (float*)d_ws;
  int*   iws = (int*)d_ws;
  int* cnt = iws + I_CNT;
  int* cur = iws + I_CUR;
  int* off = iws + I_OFF;
  int* sed = iws + I_SLOT;
  unsigned int* pqw = (unsigned int*)(ws + F_PQ);

  const size_t need2 = ((size_t)F_DYN + 2 * (XT_SZ + AGG_SZ + YZ_SZ)) * 4;
  const bool batched = ws_size >= need2;
  const int nb = batched ? 2 : 1;
  float* XT  = ws + F_DYN;
  float* AGG = XT + (size_t)nb * XT_SZ;
  float* YZ  = AGG + (size_t)nb * AGG_SZ;

  const int initg = batched ? (1 + ZBLK + 2 * TRB) : (1 + ZBLK);
  k_init<<<initg, 256, 0, stream>>>(
      w1, b1, w2, b2, attn_w, attn_a, w_ih, b_ih, b_hh, ws, cnt, out,
      tend, peri, XT, XT_SZ);
  k_count<<<(NH * NE * NS) / 256, 256, 0, stream>>>(edges, cnt);
  k_scan<<<NH, 1024, 0, stream>>>(cnt, off, ws + F_INV, ws + F_M);

  const int g_eagg = (NH * NE * 12 * 8) / 256;   // 576
  const int g_vg   = (NH * NV * 12 + 255) / 256;
  const int g_attn = (NV * 12 + 255) / 256;
  if (batched) {
    k_fe1<<<192 + 2 * g_eagg, 256, 0, stream>>>(edges, off, cur, sed, XT, XT_SZ, AGG, AGG_SZ);
    k_vg<<<dim3(g_vg, 2), 256, 0, stream>>>(cnt, off, sed, AGG, AGG_SZ, YZ, YZ_SZ);
    k_eagg2<<<dim3(g_eagg, 2), 256, 0, stream>>>(edges, YZ, YZ_SZ, ws + F_INV, AGG, AGG_SZ);
    k_vgattn<<<dim3(g_attn, 2), 256, 0, stream>>>(cnt, off, sed, AGG, AGG_SZ,
                                                  ws + F_INV, ws + F_M, ws, pqw, 0);
  } else {
    k_fill<<<(NH * NE * NS) / 256, 256, 0, stream>>>(edges, off, cur, sed);
    for (int br = 0; br < 2; ++br) {
      const float* seq = br ? peri : tend;
      k_trans2<<<dim3(TRB, 1), 256, 0, stream>>>(seq, seq, XT, 0);
      k_eagg1<<<dim3(g_eagg, 1), 256, 0, stream>>>(edges, XT, 0, AGG, 0);
      k_vg<<<dim3(g_vg, 1), 256, 0, stream>>>(cnt, off, sed, AGG, 0, YZ, 0);
      k_eagg2<<<dim3(g_eagg, 1), 256, 0, stream>>>(edges, YZ, 0, ws + F_INV, AGG, 0);
      k_vgattn<<<dim3(g_attn, 1), 256, 0, stream>>>(cnt, off, sed, AGG, 0,
                                                    ws + F_INV, ws + F_M, ws, pqw, br);
    }
  }
  k_lstm2<<<NVT * NB * 2, 256, 0, stream>>>(w_hh, ws, pqw, w_out, b_out, out);
}